// Round 1
// baseline (221.571 us; speedup 1.0000x reference)
//
#include <hip/hip_runtime.h>
#include <stdint.h>

#define BB 16
#define SS 10
#define CLSN 4
#define FGN 3
#define HH 192
#define WW 192
#define NPIX (HH * WW)   // 36864
#define WPR 3            // 64-bit words per row (192 = 3*64)
#define NWORDS (HH * WPR) // 576

typedef unsigned long long u64;

__global__ __launch_bounds__(256) void cc_loss_kernel(
    const float* __restrict__ preds,
    const int* __restrict__ samples,
    double* __restrict__ acc)
{
    __shared__ u64 fgw[NWORDS];   // fg bitboard
    __shared__ u64 cA[NWORDS];    // flood buffers
    __shared__ u64 cB[NWORDS];
    __shared__ unsigned int wkey[4];
    __shared__ double wsum[4];
    __shared__ unsigned int seedIdx;

    const int task = blockIdx.x;
    const int c = task % FGN + 1;
    const int s = (task / FGN) % SS;
    const int b = task / (FGN * SS);

    const int tid  = threadIdx.x;
    const int lane = tid & 63;
    const int wv   = tid >> 6;

    const int* smp = samples + (size_t)(b * SS + s) * NPIX;

    // ---- Phase A: build fg bitboard (coalesced load + ballot) ----
    for (int k = wv; k < NWORDS; k += 4) {
        int pix = (k << 6) + lane;
        u64 m = __ballot(smp[pix] == c);
        if (lane == 0) fgw[k] = m;
    }
    __syncthreads();

    // ---- Phase B: nb = conv3x3(fg)*fg, argmax with first-max tie-break ----
    unsigned int bestkey = 0u;
    for (int k = wv; k < NWORDS; k += 4) {
        int r = k / WPR, w = k - r * WPR;
        u64 a[3][3];
        #pragma unroll
        for (int i = 0; i < 3; ++i) {
            int rr = r + i - 1;
            #pragma unroll
            for (int j = 0; j < 3; ++j) {
                int ww = w + j - 1;
                a[i][j] = (rr >= 0 && rr < HH && ww >= 0 && ww < WPR)
                          ? fgw[rr * WPR + ww] : 0ULL;
            }
        }
        if ((a[1][1] >> lane) & 1ULL) {
            int cnt = 0;
            #pragma unroll
            for (int i = 0; i < 3; ++i) {
                u64 cu = a[i][1];
                u64 ls = (cu << 1) | (a[i][0] >> 63);
                u64 rs = (cu >> 1) | (a[i][2] << 63);
                cnt += (int)((cu >> lane) & 1ULL)
                     + (int)((ls >> lane) & 1ULL)
                     + (int)((rs >> lane) & 1ULL);
            }
            unsigned int pix = (unsigned)((k << 6) + lane);
            unsigned int key = ((unsigned)cnt << 16) | (unsigned)(NPIX - 1 - pix);
            if (key > bestkey) bestkey = key;
        }
    }
    #pragma unroll
    for (int off = 32; off > 0; off >>= 1) {
        unsigned int o = (unsigned int)__shfl_xor((int)bestkey, off, 64);
        if (o > bestkey) bestkey = o;
    }
    if (lane == 0) wkey[wv] = bestkey;
    __syncthreads();
    if (tid == 0) {
        unsigned int kk = wkey[0];
        if (wkey[1] > kk) kk = wkey[1];
        if (wkey[2] > kk) kk = wkey[2];
        if (wkey[3] > kk) kk = wkey[3];
        seedIdx = (unsigned)(NPIX - 1) - (kk & 0xFFFFu);
    }
    __syncthreads();

    // ---- Phase C: flood fill (iterated 3x3 dilation ∩ fg, double-buffered) ----
    const unsigned int seed = seedIdx;
    for (int k = tid; k < NWORDS; k += 256) {
        u64 m = 0ULL;
        if ((unsigned)k == (seed >> 6)) m = (1ULL << (seed & 63)) & fgw[k];
        cA[k] = m;
        cB[k] = 0ULL;
    }
    __syncthreads();

    u64* cur = cA;
    u64* nxt = cB;
    for (;;) {
        int changed = 0;
        if (tid < HH) {
            const int base = tid * WPR;
            u64 o0 = cur[base + 0], o1 = cur[base + 1], o2 = cur[base + 2];
            u64 u0 = o0, u1 = o1, u2 = o2;
            if (tid > 0) {
                u0 |= cur[base - 3]; u1 |= cur[base - 2]; u2 |= cur[base - 1];
            }
            if (tid < HH - 1) {
                u0 |= cur[base + 3]; u1 |= cur[base + 4]; u2 |= cur[base + 5];
            }
            u64 d0 = u0 | (u0 << 1) | (u0 >> 1) | (u1 << 63);
            u64 d1 = u1 | (u1 << 1) | (u0 >> 63) | (u1 >> 1) | (u2 << 63);
            u64 d2 = u2 | (u2 << 1) | (u1 >> 63) | (u2 >> 1);
            d0 &= fgw[base + 0]; d1 &= fgw[base + 1]; d2 &= fgw[base + 2];
            nxt[base + 0] = d0; nxt[base + 1] = d1; nxt[base + 2] = d2;
            changed = (d0 != o0) || (d1 != o1) || (d2 != o2);
        }
        int any = __syncthreads_or(changed);
        u64* t = cur; cur = nxt; nxt = t;  // cur = latest
        if (!any) break;
    }

    // ---- Phase D: reward-weighted log-prob partial sum ----
    // per_c = comp ? conv3x3(comp)/9 : (fg ? -1 : 0); logp = log(preds[b,c,pix]+1e-8)
    float facc = 0.0f;
    const float* pp = preds + (size_t)(b * CLSN + c) * NPIX;
    for (int k = wv; k < NWORDS; k += 4) {
        u64 fgword = fgw[k];
        if (fgword == 0ULL) continue;      // wave-uniform skip
        int r = k / WPR, w = k - r * WPR;
        u64 a[3][3];
        #pragma unroll
        for (int i = 0; i < 3; ++i) {
            int rr = r + i - 1;
            #pragma unroll
            for (int j = 0; j < 3; ++j) {
                int ww = w + j - 1;
                a[i][j] = (rr >= 0 && rr < HH && ww >= 0 && ww < WPR)
                          ? cur[rr * WPR + ww] : 0ULL;
            }
        }
        bool compbit = ((a[1][1] >> lane) & 1ULL) != 0ULL;
        bool fgbit   = ((fgword  >> lane) & 1ULL) != 0ULL;
        float coef = 0.0f;
        if (compbit) {
            int cnt = 0;
            #pragma unroll
            for (int i = 0; i < 3; ++i) {
                u64 cu = a[i][1];
                u64 ls = (cu << 1) | (a[i][0] >> 63);
                u64 rs = (cu >> 1) | (a[i][2] << 63);
                cnt += (int)((cu >> lane) & 1ULL)
                     + (int)((ls >> lane) & 1ULL)
                     + (int)((rs >> lane) & 1ULL);
            }
            coef = (float)cnt / 9.0f;
        } else if (fgbit) {
            coef = -1.0f;
        }
        if (coef != 0.0f) {
            float p = pp[(k << 6) + lane];
            facc += coef * __logf(p + 1e-8f);
        }
    }

    #pragma unroll
    for (int off = 32; off > 0; off >>= 1)
        facc += __shfl_xor(facc, off, 64);
    if (lane == 0) wsum[wv] = (double)facc;
    __syncthreads();
    if (tid == 0) {
        atomicAdd(acc, wsum[0] + wsum[1] + wsum[2] + wsum[3]);
    }
}

__global__ void finalize_kernel(const double* __restrict__ acc, float* __restrict__ out)
{
    if (threadIdx.x == 0 && blockIdx.x == 0) {
        out[0] = (float)(-acc[0] / (double)((long long)BB * SS * NPIX));
    }
}

extern "C" void kernel_launch(void* const* d_in, const int* in_sizes, int n_in,
                              void* d_out, int out_size, void* d_ws, size_t ws_size,
                              hipStream_t stream)
{
    const float* preds   = (const float*)d_in[0];
    const int*   samples = (const int*)d_in[1];
    double* acc = (double*)d_ws;

    hipMemsetAsync(acc, 0, sizeof(double), stream);
    hipLaunchKernelGGL(cc_loss_kernel, dim3(BB * SS * FGN), dim3(256), 0, stream,
                       preds, samples, acc);
    hipLaunchKernelGGL(finalize_kernel, dim3(1), dim3(64), 0, stream,
                       acc, (float*)d_out);
}

// Round 2
// 54.164 us; speedup vs baseline: 4.0908x; 4.0908x over previous
//
#include <hip/hip_runtime.h>
#include <stdint.h>

#define BB 16
#define SS 10
#define CLSN 4
#define FGN 3
#define HH 192
#define WW 192
#define NPIX (HH * WW)    // 36864
#define WPR 3             // u64 words per row
#define NWORDS (HH * WPR) // 576

typedef unsigned long long u64;

// full adder: s = a^b^c, cy = majority(a,b,c)
#define FAD(a, b, c, s, cy)            \
    do {                               \
        u64 t_ = (a) ^ (b);            \
        (s) = t_ ^ (c);                \
        (cy) = ((a) & (b)) | (t_ & (c)); \
    } while (0)

// horizontal +/-1 smear of a 3-word row (192 bits)
#define SMEAR3(u0, u1, u2, s0, s1, s2)                          \
    do {                                                        \
        (s0) = (u0) | ((u0) << 1) | ((u0) >> 1) | ((u1) << 63); \
        (s1) = (u1) | ((u1) << 1) | ((u0) >> 63) | ((u1) >> 1) | ((u2) << 63); \
        (s2) = (u2) | ((u2) << 1) | ((u1) >> 63) | ((u2) >> 1); \
    } while (0)

// bit-sliced 3x3 ones-conv of bitboard `bd` for word k: 4 count bit-planes + center word
__device__ __forceinline__ void plane9(const u64* bd, int k,
                                       u64& P0, u64& P1, u64& P2, u64& P3, u64& mid)
{
    const int r = k / WPR;
    const int wc = k - r * WPR;
    u64 rows[3][3];
#pragma unroll
    for (int di = 0; di < 3; ++di) {
        int rr = r + di - 1;
#pragma unroll
        for (int dj = 0; dj < 3; ++dj) {
            int ww = wc + dj - 1;
            rows[di][dj] = (rr >= 0 && rr < HH && ww >= 0 && ww < WPR)
                           ? bd[rr * WPR + ww] : 0ULL;
        }
    }
    mid = rows[1][1];
    u64 in[9];
#pragma unroll
    for (int i = 0; i < 3; ++i) {
        u64 m = rows[i][1], lf = rows[i][0], rg = rows[i][2];
        in[3 * i + 0] = m;
        in[3 * i + 1] = (m << 1) | (lf >> 63);
        in[3 * i + 2] = (m >> 1) | (rg << 63);
    }
    u64 s0a, c0a, s0b, c0b, s0c, c0c, c0d, s1a, c1a, c1b;
    FAD(in[0], in[1], in[2], s0a, c0a);
    FAD(in[3], in[4], in[5], s0b, c0b);
    FAD(in[6], in[7], in[8], s0c, c0c);
    FAD(s0a, s0b, s0c, P0, c0d);
    FAD(c0a, c0b, c0c, s1a, c1a);
    P1 = s1a ^ c0d;
    c1b = s1a & c0d;
    P2 = c1a ^ c1b;
    P3 = c1a & c1b;
}

__global__ __launch_bounds__(256) void cc_loss_kernel(
    const float* __restrict__ preds,
    const int* __restrict__ samples,
    double* __restrict__ acc)
{
    __shared__ u64 fgw[NWORDS];
    __shared__ u64 compB[NWORDS];
    __shared__ u64 pl[4][NWORDS];
    __shared__ unsigned int wkey[4];
    __shared__ double wsum[4];
    __shared__ unsigned int seedIdx;

    const int task = blockIdx.x;
    const int c = task % FGN + 1;
    const int s = (task / FGN) % SS;
    const int b = task / (FGN * SS);

    const int tid  = threadIdx.x;
    const int lane = tid & 63;
    const int wv   = tid >> 6;

    const int* smp = samples + (size_t)(b * SS + s) * NPIX;

    // ---- Phase A: build fg bitboard, 8 loads in flight ----
    {
        const int base = wv * 144;
        for (int i = 0; i < 144; i += 8) {
            int v[8];
#pragma unroll
            for (int j = 0; j < 8; ++j)
                v[j] = smp[((base + i + j) << 6) + lane];
#pragma unroll
            for (int j = 0; j < 8; ++j) {
                u64 m = __ballot(v[j] == c);
                if (lane == 0) fgw[base + i + j] = m;
            }
        }
    }
    __syncthreads();

    // ---- Phase B: bit-sliced neighbor counts -> argmax seed (first-max tie-break) ----
    {
        unsigned int bestkey = 0u;
        for (int k = tid; k < NWORDS; k += 256) {
            u64 P0, P1, P2, P3, mid;
            plane9(fgw, k, P0, P1, P2, P3, mid);
            if (mid) {
                u64 cand = mid, t;
                unsigned v = 0;
                t = cand & P3; if (t) { cand = t; v |= 8u; }
                t = cand & P2; if (t) { cand = t; v |= 4u; }
                t = cand & P1; if (t) { cand = t; v |= 2u; }
                t = cand & P0; if (t) { cand = t; v |= 1u; }
                unsigned pix = ((unsigned)k << 6) + (unsigned)(__ffsll(cand) - 1);
                unsigned key = (v << 16) | (36863u - pix);
                if (key > bestkey) bestkey = key;
            }
        }
#pragma unroll
        for (int off = 32; off > 0; off >>= 1) {
            unsigned int o = (unsigned int)__shfl_xor((int)bestkey, off, 64);
            if (o > bestkey) bestkey = o;
        }
        if (lane == 0) wkey[wv] = bestkey;
    }
    __syncthreads();
    if (tid == 0) {
        unsigned int kk = wkey[0];
        if (wkey[1] > kk) kk = wkey[1];
        if (wkey[2] > kk) kk = wkey[2];
        if (wkey[3] > kk) kk = wkey[3];
        seedIdx = 36863u - (kk & 0xFFFFu);
    }
    __syncthreads();

    // ---- Phase C: register flood fill on wave 0 (lane l owns rows 3l..3l+2) ----
    if (wv == 0) {
        const unsigned seed = seedIdx;
        u64 f[3][3], cc[3][3];
        const int rbase = 3 * lane;
#pragma unroll
        for (int j = 0; j < 3; ++j)
#pragma unroll
            for (int w = 0; w < 3; ++w) {
                f[j][w] = fgw[(rbase + j) * WPR + w];
                cc[j][w] = 0ULL;
            }
        {
            const int sr = seed / WW, sw = (seed % WW) >> 6, sb = seed & 63;
            if (sr / 3 == lane)
                cc[sr % 3][sw] = (1ULL << sb) & f[sr % 3][sw];
        }
        for (;;) {
            u64 bA0 = __shfl_up(cc[2][0], 1, 64);
            u64 bA1 = __shfl_up(cc[2][1], 1, 64);
            u64 bA2 = __shfl_up(cc[2][2], 1, 64);
            u64 tB0 = __shfl_down(cc[0][0], 1, 64);
            u64 tB1 = __shfl_down(cc[0][1], 1, 64);
            u64 tB2 = __shfl_down(cc[0][2], 1, 64);
            if (lane == 0)  { bA0 = bA1 = bA2 = 0ULL; }
            if (lane == 63) { tB0 = tB1 = tB2 = 0ULL; }

            u64 o00 = cc[0][0], o01 = cc[0][1], o02 = cc[0][2];
            u64 o10 = cc[1][0], o11 = cc[1][1], o12 = cc[1][2];
            u64 o20 = cc[2][0], o21 = cc[2][1], o22 = cc[2][2];

            u64 u0, u1, u2, s0, s1, s2;
            // down pass
            u0 = bA0 | cc[0][0] | cc[1][0]; u1 = bA1 | cc[0][1] | cc[1][1]; u2 = bA2 | cc[0][2] | cc[1][2];
            SMEAR3(u0, u1, u2, s0, s1, s2);
            cc[0][0] = s0 & f[0][0]; cc[0][1] = s1 & f[0][1]; cc[0][2] = s2 & f[0][2];

            u0 = cc[0][0] | cc[1][0] | cc[2][0]; u1 = cc[0][1] | cc[1][1] | cc[2][1]; u2 = cc[0][2] | cc[1][2] | cc[2][2];
            SMEAR3(u0, u1, u2, s0, s1, s2);
            cc[1][0] = s0 & f[1][0]; cc[1][1] = s1 & f[1][1]; cc[1][2] = s2 & f[1][2];

            u0 = cc[1][0] | cc[2][0] | tB0; u1 = cc[1][1] | cc[2][1] | tB1; u2 = cc[1][2] | cc[2][2] | tB2;
            SMEAR3(u0, u1, u2, s0, s1, s2);
            cc[2][0] = s0 & f[2][0]; cc[2][1] = s1 & f[2][1]; cc[2][2] = s2 & f[2][2];

            // up pass
            u0 = cc[0][0] | cc[1][0] | cc[2][0]; u1 = cc[0][1] | cc[1][1] | cc[2][1]; u2 = cc[0][2] | cc[1][2] | cc[2][2];
            SMEAR3(u0, u1, u2, s0, s1, s2);
            cc[1][0] = s0 & f[1][0]; cc[1][1] = s1 & f[1][1]; cc[1][2] = s2 & f[1][2];

            u0 = bA0 | cc[0][0] | cc[1][0]; u1 = bA1 | cc[0][1] | cc[1][1]; u2 = bA2 | cc[0][2] | cc[1][2];
            SMEAR3(u0, u1, u2, s0, s1, s2);
            cc[0][0] = s0 & f[0][0]; cc[0][1] = s1 & f[0][1]; cc[0][2] = s2 & f[0][2];

            u64 d = (cc[0][0] ^ o00) | (cc[0][1] ^ o01) | (cc[0][2] ^ o02)
                  | (cc[1][0] ^ o10) | (cc[1][1] ^ o11) | (cc[1][2] ^ o12)
                  | (cc[2][0] ^ o20) | (cc[2][1] ^ o21) | (cc[2][2] ^ o22);
            if (!__any(d != 0ULL)) break;
        }
#pragma unroll
        for (int j = 0; j < 3; ++j)
#pragma unroll
            for (int w = 0; w < 3; ++w)
                compB[(rbase + j) * WPR + w] = cc[j][w];
    }
    __syncthreads();

    // ---- Phase D1: bit-sliced counts of comp -> LDS planes ----
    for (int k = tid; k < NWORDS; k += 256) {
        u64 P0, P1, P2, P3, mid;
        plane9(compB, k, P0, P1, P2, P3, mid);
        pl[0][k] = P0; pl[1][k] = P1; pl[2][k] = P2; pl[3][k] = P3;
    }
    __syncthreads();

    // ---- Phase D2: reward-weighted log-prob accumulation ----
    float facc = 0.0f;
    {
        const float* pp = preds + ((size_t)b * CLSN + c) * NPIX;
        const int dbase = wv * 144;
        for (int i = 0; i < 144; i += 4) {
            float pv[4];
            u64 fw[4], cw[4], q0[4], q1[4], q2[4], q3[4];
#pragma unroll
            for (int j = 0; j < 4; ++j) {
                int k = dbase + i + j;
                pv[j] = pp[(k << 6) + lane];
                fw[j] = fgw[k];
                cw[j] = compB[k];
                q0[j] = pl[0][k]; q1[j] = pl[1][k]; q2[j] = pl[2][k]; q3[j] = pl[3][k];
            }
#pragma unroll
            for (int j = 0; j < 4; ++j) {
                float lp = __logf(pv[j] + 1e-8f);
                int fgbit = (int)((fw[j] >> lane) & 1ULL);
                int cbit  = (int)((cw[j] >> lane) & 1ULL);
                int cnt = (int)((q0[j] >> lane) & 1ULL)
                        | ((int)((q1[j] >> lane) & 1ULL) << 1)
                        | ((int)((q2[j] >> lane) & 1ULL) << 2)
                        | ((int)((q3[j] >> lane) & 1ULL) << 3);
                float coef = cbit ? (float)cnt / 9.0f : (fgbit ? -1.0f : 0.0f);
                facc += coef * lp;
            }
        }
    }
#pragma unroll
    for (int off = 32; off > 0; off >>= 1)
        facc += __shfl_xor(facc, off, 64);
    if (lane == 0) wsum[wv] = (double)facc;
    __syncthreads();
    if (tid == 0)
        atomicAdd(acc, wsum[0] + wsum[1] + wsum[2] + wsum[3]);
}

__global__ void finalize_kernel(const double* __restrict__ acc, float* __restrict__ out)
{
    if (threadIdx.x == 0 && blockIdx.x == 0)
        out[0] = (float)(-acc[0] / (double)((long long)BB * SS * NPIX));
}

extern "C" void kernel_launch(void* const* d_in, const int* in_sizes, int n_in,
                              void* d_out, int out_size, void* d_ws, size_t ws_size,
                              hipStream_t stream)
{
    const float* preds   = (const float*)d_in[0];
    const int*   samples = (const int*)d_in[1];
    double* acc = (double*)d_ws;

    hipMemsetAsync(acc, 0, sizeof(double), stream);
    hipLaunchKernelGGL(cc_loss_kernel, dim3(BB * SS * FGN), dim3(256), 0, stream,
                       preds, samples, acc);
    hipLaunchKernelGGL(finalize_kernel, dim3(1), dim3(64), 0, stream,
                       acc, (float*)d_out);
}

// Round 3
// 48.833 us; speedup vs baseline: 4.5373x; 1.1092x over previous
//
#include <hip/hip_runtime.h>
#include <stdint.h>

#define BB 16
#define SS 10
#define CLSN 4
#define FGN 3
#define HH 192
#define WW 192
#define NPIX (HH * WW)    // 36864
#define WPR 3             // u64 words per row
#define NWORDS (HH * WPR) // 576
#define NTHREADS 1024
#define NWAVES 16
#define CHUNK (NWORDS / NWAVES)  // 36 words per wave

typedef unsigned long long u64;

// full adder: s = a^b^c, cy = majority(a,b,c)
#define FAD(a, b, c, s, cy)            \
    do {                               \
        u64 t_ = (a) ^ (b);            \
        (s) = t_ ^ (c);                \
        (cy) = ((a) & (b)) | (t_ & (c)); \
    } while (0)

// horizontal +/-1 smear of a 3-word row (192 bits)
#define SMEAR3(u0, u1, u2, s0, s1, s2)                          \
    do {                                                        \
        (s0) = (u0) | ((u0) << 1) | ((u0) >> 1) | ((u1) << 63); \
        (s1) = (u1) | ((u1) << 1) | ((u0) >> 63) | ((u1) >> 1) | ((u2) << 63); \
        (s2) = (u2) | ((u2) << 1) | ((u1) >> 63) | ((u2) >> 1); \
    } while (0)

// bit-sliced 3x3 ones-conv of bitboard `bd` for word k: 4 count bit-planes + center word
__device__ __forceinline__ void plane9(const u64* bd, int k,
                                       u64& P0, u64& P1, u64& P2, u64& P3, u64& mid)
{
    const int r = k / WPR;
    const int wc = k - r * WPR;
    u64 rows[3][3];
#pragma unroll
    for (int di = 0; di < 3; ++di) {
        int rr = r + di - 1;
#pragma unroll
        for (int dj = 0; dj < 3; ++dj) {
            int ww = wc + dj - 1;
            rows[di][dj] = (rr >= 0 && rr < HH && ww >= 0 && ww < WPR)
                           ? bd[rr * WPR + ww] : 0ULL;
        }
    }
    mid = rows[1][1];
    u64 in[9];
#pragma unroll
    for (int i = 0; i < 3; ++i) {
        u64 m = rows[i][1], lf = rows[i][0], rg = rows[i][2];
        in[3 * i + 0] = m;
        in[3 * i + 1] = (m << 1) | (lf >> 63);
        in[3 * i + 2] = (m >> 1) | (rg << 63);
    }
    u64 s0a, c0a, s0b, c0b, s0c, c0c, c0d, s1a, c1a, c1b;
    FAD(in[0], in[1], in[2], s0a, c0a);
    FAD(in[3], in[4], in[5], s0b, c0b);
    FAD(in[6], in[7], in[8], s0c, c0c);
    FAD(s0a, s0b, s0c, P0, c0d);
    FAD(c0a, c0b, c0c, s1a, c1a);
    P1 = s1a ^ c0d;
    c1b = s1a & c0d;
    P2 = c1a ^ c1b;
    P3 = c1a & c1b;
}

__global__ __launch_bounds__(NTHREADS) void cc_loss_kernel(
    const float* __restrict__ preds,
    const int* __restrict__ samples,
    double* __restrict__ acc)
{
    __shared__ u64 fgw[NWORDS];
    __shared__ u64 compB[NWORDS];
    __shared__ u64 pl[4][NWORDS];
    __shared__ unsigned int wkey[NWAVES];
    __shared__ double wsum[NWAVES];
    __shared__ unsigned int seedIdx;

    // XCD-locality mapping: tasks 160 apart share (b,s) and 160%8==0 ->
    // the 3 class-tasks of one (b,s) land on the same XCD -> samples L2 reuse.
    const int blk = blockIdx.x;
    const int c = 1 + blk / (BB * SS);
    const int pair = blk % (BB * SS);
    const int b = pair / SS;
    const int s = pair % SS;

    const int tid  = threadIdx.x;
    const int lane = tid & 63;
    const int wv   = tid >> 6;

    const int* smp = samples + (size_t)pair * NPIX;

    // ---- Phase A: build fg bitboard (coalesced loads + ballot) ----
    {
        const int base = wv * CHUNK;
        for (int i = 0; i < CHUNK; i += 6) {
            int v[6];
#pragma unroll
            for (int j = 0; j < 6; ++j)
                v[j] = smp[((base + i + j) << 6) + lane];
#pragma unroll
            for (int j = 0; j < 6; ++j) {
                u64 m = __ballot(v[j] == c);
                if (lane == 0) fgw[base + i + j] = m;
            }
        }
    }
    __syncthreads();

    // ---- Phase B: bit-sliced neighbor counts -> argmax seed (first-max tie-break) ----
    {
        unsigned int bestkey = 0u;
        if (tid < NWORDS) {
            u64 P0, P1, P2, P3, mid;
            plane9(fgw, tid, P0, P1, P2, P3, mid);
            if (mid) {
                u64 cand = mid, t;
                unsigned v = 0;
                t = cand & P3; if (t) { cand = t; v |= 8u; }
                t = cand & P2; if (t) { cand = t; v |= 4u; }
                t = cand & P1; if (t) { cand = t; v |= 2u; }
                t = cand & P0; if (t) { cand = t; v |= 1u; }
                unsigned pix = ((unsigned)tid << 6) + (unsigned)(__ffsll(cand) - 1);
                bestkey = (v << 16) | (36863u - pix);
            }
        }
#pragma unroll
        for (int off = 32; off > 0; off >>= 1) {
            unsigned int o = (unsigned int)__shfl_xor((int)bestkey, off, 64);
            if (o > bestkey) bestkey = o;
        }
        if (lane == 0) wkey[wv] = bestkey;
    }
    __syncthreads();
    if (tid == 0) {
        unsigned int kk = 0u;
#pragma unroll
        for (int i = 0; i < NWAVES; ++i)
            if (wkey[i] > kk) kk = wkey[i];
        seedIdx = 36863u - (kk & 0xFFFFu);
    }
    __syncthreads();

    // ---- Phase C: register flood fill on wave 0 (lane l owns rows 3l..3l+2) ----
    if (wv == 0) {
        const unsigned seed = seedIdx;
        u64 f[3][3], cc[3][3];
        const int rbase = 3 * lane;
#pragma unroll
        for (int j = 0; j < 3; ++j)
#pragma unroll
            for (int w = 0; w < 3; ++w) {
                f[j][w] = fgw[(rbase + j) * WPR + w];
                cc[j][w] = 0ULL;
            }
        {
            const int sr = seed / WW, sw = (seed % WW) >> 6, sb = seed & 63;
            if (sr / 3 == lane)
                cc[sr % 3][sw] = (1ULL << sb) & f[sr % 3][sw];
        }
        for (;;) {
            u64 bA0 = __shfl_up(cc[2][0], 1, 64);
            u64 bA1 = __shfl_up(cc[2][1], 1, 64);
            u64 bA2 = __shfl_up(cc[2][2], 1, 64);
            u64 tB0 = __shfl_down(cc[0][0], 1, 64);
            u64 tB1 = __shfl_down(cc[0][1], 1, 64);
            u64 tB2 = __shfl_down(cc[0][2], 1, 64);
            if (lane == 0)  { bA0 = bA1 = bA2 = 0ULL; }
            if (lane == 63) { tB0 = tB1 = tB2 = 0ULL; }

            u64 o00 = cc[0][0], o01 = cc[0][1], o02 = cc[0][2];
            u64 o10 = cc[1][0], o11 = cc[1][1], o12 = cc[1][2];
            u64 o20 = cc[2][0], o21 = cc[2][1], o22 = cc[2][2];

            u64 u0, u1, u2, s0, s1, s2;
            // down pass
            u0 = bA0 | cc[0][0] | cc[1][0]; u1 = bA1 | cc[0][1] | cc[1][1]; u2 = bA2 | cc[0][2] | cc[1][2];
            SMEAR3(u0, u1, u2, s0, s1, s2);
            cc[0][0] = s0 & f[0][0]; cc[0][1] = s1 & f[0][1]; cc[0][2] = s2 & f[0][2];

            u0 = cc[0][0] | cc[1][0] | cc[2][0]; u1 = cc[0][1] | cc[1][1] | cc[2][1]; u2 = cc[0][2] | cc[1][2] | cc[2][2];
            SMEAR3(u0, u1, u2, s0, s1, s2);
            cc[1][0] = s0 & f[1][0]; cc[1][1] = s1 & f[1][1]; cc[1][2] = s2 & f[1][2];

            u0 = cc[1][0] | cc[2][0] | tB0; u1 = cc[1][1] | cc[2][1] | tB1; u2 = cc[1][2] | cc[2][2] | tB2;
            SMEAR3(u0, u1, u2, s0, s1, s2);
            cc[2][0] = s0 & f[2][0]; cc[2][1] = s1 & f[2][1]; cc[2][2] = s2 & f[2][2];

            // up pass
            u0 = cc[0][0] | cc[1][0] | cc[2][0]; u1 = cc[0][1] | cc[1][1] | cc[2][1]; u2 = cc[0][2] | cc[1][2] | cc[2][2];
            SMEAR3(u0, u1, u2, s0, s1, s2);
            cc[1][0] = s0 & f[1][0]; cc[1][1] = s1 & f[1][1]; cc[1][2] = s2 & f[1][2];

            u0 = bA0 | cc[0][0] | cc[1][0]; u1 = bA1 | cc[0][1] | cc[1][1]; u2 = bA2 | cc[0][2] | cc[1][2];
            SMEAR3(u0, u1, u2, s0, s1, s2);
            cc[0][0] = s0 & f[0][0]; cc[0][1] = s1 & f[0][1]; cc[0][2] = s2 & f[0][2];

            u64 d = (cc[0][0] ^ o00) | (cc[0][1] ^ o01) | (cc[0][2] ^ o02)
                  | (cc[1][0] ^ o10) | (cc[1][1] ^ o11) | (cc[1][2] ^ o12)
                  | (cc[2][0] ^ o20) | (cc[2][1] ^ o21) | (cc[2][2] ^ o22);
            if (!__any(d != 0ULL)) break;
        }
#pragma unroll
        for (int j = 0; j < 3; ++j)
#pragma unroll
            for (int w = 0; w < 3; ++w)
                compB[(rbase + j) * WPR + w] = cc[j][w];
    }
    __syncthreads();

    // ---- Phase D1: bit-sliced counts of comp -> LDS planes (1 word/thread) ----
    if (tid < NWORDS) {
        u64 P0, P1, P2, P3, mid;
        plane9(compB, tid, P0, P1, P2, P3, mid);
        pl[0][tid] = P0; pl[1][tid] = P1; pl[2][tid] = P2; pl[3][tid] = P3;
    }
    __syncthreads();

    // ---- Phase D2: reward-weighted log-prob accumulation ----
    float facc = 0.0f;
    {
        const float* pp = preds + ((size_t)b * CLSN + c) * NPIX;
        const int dbase = wv * CHUNK;
        for (int i = 0; i < CHUNK; i += 4) {
            float pv[4];
            u64 fw[4], cw[4], q0[4], q1[4], q2[4], q3[4];
#pragma unroll
            for (int j = 0; j < 4; ++j) {
                int k = dbase + i + j;
                pv[j] = pp[(k << 6) + lane];
                fw[j] = fgw[k];
                cw[j] = compB[k];
                q0[j] = pl[0][k]; q1[j] = pl[1][k]; q2[j] = pl[2][k]; q3[j] = pl[3][k];
            }
#pragma unroll
            for (int j = 0; j < 4; ++j) {
                float lp = __logf(pv[j] + 1e-8f);
                int fgbit = (int)((fw[j] >> lane) & 1ULL);
                int cbit  = (int)((cw[j] >> lane) & 1ULL);
                int cnt = (int)((q0[j] >> lane) & 1ULL)
                        | ((int)((q1[j] >> lane) & 1ULL) << 1)
                        | ((int)((q2[j] >> lane) & 1ULL) << 2)
                        | ((int)((q3[j] >> lane) & 1ULL) << 3);
                float coef = cbit ? (float)cnt / 9.0f : (fgbit ? -1.0f : 0.0f);
                facc += coef * lp;
            }
        }
    }
#pragma unroll
    for (int off = 32; off > 0; off >>= 1)
        facc += __shfl_xor(facc, off, 64);
    if (lane == 0) wsum[wv] = (double)facc;
    __syncthreads();
    if (tid == 0) {
        double t = 0.0;
#pragma unroll
        for (int i = 0; i < NWAVES; ++i) t += wsum[i];
        atomicAdd(acc, t);
    }
}

__global__ void finalize_kernel(const double* __restrict__ acc, float* __restrict__ out)
{
    if (threadIdx.x == 0 && blockIdx.x == 0)
        out[0] = (float)(-acc[0] / (double)((long long)BB * SS * NPIX));
}

extern "C" void kernel_launch(void* const* d_in, const int* in_sizes, int n_in,
                              void* d_out, int out_size, void* d_ws, size_t ws_size,
                              hipStream_t stream)
{
    const float* preds   = (const float*)d_in[0];
    const int*   samples = (const int*)d_in[1];
    double* acc = (double*)d_ws;

    hipMemsetAsync(acc, 0, sizeof(double), stream);
    hipLaunchKernelGGL(cc_loss_kernel, dim3(BB * SS * FGN), dim3(NTHREADS), 0, stream,
                       preds, samples, acc);
    hipLaunchKernelGGL(finalize_kernel, dim3(1), dim3(64), 0, stream,
                       acc, (float*)d_out);
}